// Round 2
// baseline (6753.377 us; speedup 1.0000x reference)
//
#include <hip/hip_runtime.h>
#include <math.h>

// ---------------- problem constants ----------------
#define B_ 8192
#define T_ 223
#define D_ 7
#define H_ 128
#define G_ 512      // 4*H
#define E_ 50
#define O_ 29
#define A_ 9
#define TD_ (T_*D_)     // 1561
#define NB 32           // batch rows per block (main kernel)
#define NTHR 512
#define MB 8            // batch rows per block (head kernel)

// ---------------- workspace layout (float offsets) ----------------
#define WS_WHHT  0                            // [128][512] transposed W_hh
#define WS_WIHT  (WS_WHHT + G_*H_)            // 65536: [14][512] transposed W_ih
#define WS_MINV  (WS_WIHT + 14*G_)            // 72704: 1/(msum_t+1e-5), T floats
#define WS_ACC   (WS_MINV + T_)               // 72927: [0]=x_loss raw sum, [1]=y_loss raw sum
#define WS_WCATT (WS_ACC + 2)                 // 72929: [178][128] transposed W_cat
#define WS_HFIN  (WS_WCATT + 178*H_)          // 95713: final h, [B][128]
#define WS_TOTAL (WS_HFIN + B_*H_)            // ~1.14M floats ~= 4.6 MB

// ---------------- output layout (floats) ----------------
#define OUT_YH  3
#define OUT_IMP (OUT_YH + B_*O_)              // 237571
#define OUT_LAB (OUT_IMP + B_*T_*D_)          // 13025283
// total out_size = 13,033,475

// NOTE: parameter names must not collide with vector member tokens x/y/z/w
#define FMA4(Pa, Ps, Pw) { (Pa).x = fmaf((Ps),(Pw).x,(Pa).x); (Pa).y = fmaf((Ps),(Pw).y,(Pa).y); \
                           (Pa).z = fmaf((Ps),(Pw).z,(Pa).z); (Pa).w = fmaf((Ps),(Pw).w,(Pa).w); }

__device__ __forceinline__ float rcp_(float x)  { return __builtin_amdgcn_rcpf(x); }
__device__ __forceinline__ float sigm(float x)  { return rcp_(1.f + __expf(-x)); }
__device__ __forceinline__ float tanh_(float x) { return 1.f - 2.f*rcp_(1.f + __expf(2.f*x)); }

// ================= prep: transposes + zero accumulators =================
__global__ void rits_prep(const float* __restrict__ W_hh, const float* __restrict__ W_ih,
                          const float* __restrict__ W_cat, float* __restrict__ ws)
{
    int idx = blockIdx.x * 256 + threadIdx.x;
    if (idx < G_*H_) {                       // W_hh [512][128] -> [128][512]
        int j = idx >> 7, k = idx & (H_-1);
        ws[WS_WHHT + k*G_ + j] = W_hh[idx];
    } else if (idx < G_*H_ + 14*G_) {        // W_ih [512][14] -> [14][512]
        int e = idx - G_*H_;
        int j = e / 14, k = e - j*14;
        ws[WS_WIHT + k*G_ + j] = W_ih[e];
    } else if (idx < G_*H_ + 14*G_ + H_*178) { // W_cat [128][178] -> [178][128]
        int e = idx - (G_*H_ + 14*G_);
        int j = e / 178, k = e - j*178;
        ws[WS_WCATT + k*H_ + j] = W_cat[e];
    }
    if (idx < 2) ws[WS_ACC + idx] = 0.f;
}

// ================= per-step mask sums: inv_t = 1/(sum(masks[:,t,:])+1e-5) =================
__global__ void rits_msum(const float* __restrict__ masks, float* __restrict__ ws)
{
    const int t = blockIdx.x, tid = threadIdx.x;
    float s = 0.f;
    for (int i = tid; i < B_*D_; i += 256) {
        int b = i / D_, q = i - b*D_;
        s += masks[b*TD_ + t*D_ + q];
    }
    for (int off = 32; off > 0; off >>= 1) s += __shfl_down(s, off, 64);
    __shared__ float r[4];
    if ((tid & 63) == 0) r[tid >> 6] = s;
    __syncthreads();
    if (tid == 0) {
        float tot = r[0] + r[1] + r[2] + r[3];
        ws[WS_MINV + t] = 1.f / (tot + 1e-5f);
    }
}

// ================= main scan kernel =================
__global__ __launch_bounds__(NTHR) void rits_main(
    const float* __restrict__ values, const float* __restrict__ masks, const float* __restrict__ deltas,
    const float* __restrict__ W_td_h, const float* __restrict__ b_td_h,
    const float* __restrict__ W_td_x, const float* __restrict__ b_td_x,
    const float* __restrict__ W_hist, const float* __restrict__ b_hist,
    const float* __restrict__ W_feat, const float* __restrict__ b_feat,
    const float* __restrict__ W_comb, const float* __restrict__ b_comb,
    const float* __restrict__ b_ih, const float* __restrict__ b_hh,
    float* __restrict__ ws, float* __restrict__ out)
{
    __shared__ __attribute__((aligned(16))) float h_lds[NB*132];   // padded stride 132
    __shared__ float4 stage4[32*128];                              // 32 k-rows of W_hhT (64 KB)
    __shared__ __attribute__((aligned(16))) float wih[14*G_];
    __shared__ float wtdh[H_*D_];
    __shared__ float btdh[H_];
    __shared__ __attribute__((aligned(16))) float whist[D_*H_];
    __shared__ __attribute__((aligned(16))) float biasg[G_];
    __shared__ float wf[D_*D_];
    __shared__ float wcomb[D_*2*D_];
    __shared__ float bhist[D_], tdx[D_], btdx[D_], bfeat[D_], bcomb[D_];
    __shared__ float xs[NB*8], msh[NB*8], dsl[NB*8], xh[NB*8], xcb[NB*8], gx[NB*8];
    __shared__ float inbuf[NB*16];   // [b][0..6]=c_c, [b][7..13]=m
    __shared__ float red[8];

    const int tid = threadIdx.x;
    const int b0  = blockIdx.x * NB;

    // ---- one-time LDS init ----
    for (int i = tid; i < H_*D_; i += NTHR) wtdh[i]  = W_td_h[i];
    for (int i = tid; i < D_*H_; i += NTHR) whist[i] = W_hist[i];
    if (tid < H_) btdh[tid] = b_td_h[tid];
    biasg[tid] = b_ih[tid] + b_hh[tid];                 // NTHR == G_
    for (int i = tid; i < 14*G_; i += NTHR) wih[i] = ws[WS_WIHT + i];
    if (tid < D_*D_)   wf[tid]    = (tid % (D_+1) == 0) ? 0.f : W_feat[tid];   // zero diagonal
    if (tid < D_*2*D_) wcomb[tid] = W_comb[tid];
    if (tid < D_) {
        bhist[tid] = b_hist[tid];
        tdx[tid]   = W_td_x[tid*D_ + tid];              // diagonal only
        btdx[tid]  = b_td_x[tid];
        bfeat[tid] = b_feat[tid];
        bcomb[tid] = b_comb[tid];
    }
    for (int i = tid; i < NB*132; i += NTHR) h_lds[i] = 0.f;

    const int jj = tid & 31;         // 32 col-groups of 4 gate-cols
    const int bg = tid >> 5;         // 16 batch-pair groups
    const int bA = bg*2, bB = bg*2 + 1;
    float4 c0 = {0.f,0.f,0.f,0.f}, c1 = {0.f,0.f,0.f,0.f};
    float lacc = 0.f;

    // input prefetch (one step ahead)
    const bool ldr = (tid < NB*D_);
    const int lb = tid / D_, li = tid - lb*D_;
    const long gbase = (long)(b0 + lb)*TD_ + li;
    float rx = 0.f, rm = 0.f, rd = 0.f;
    if (ldr) { rx = values[gbase]; rm = masks[gbase]; rd = deltas[gbase]; }

    const float*  minv  = ws + WS_MINV;
    const float4* wih4  = (const float4*)wih;
    const float4* whhT4 = (const float4*)(ws + WS_WHHT);

    for (int t = 0; t < T_; ++t) {
        if (ldr) {
            xs[lb*8+li] = rx; msh[lb*8+li] = rm; dsl[lb*8+li] = rd;
            inbuf[lb*16 + 7 + li] = rm;
        }
        __syncthreads();   // also orders previous step's h writes before A1
        if (ldr && t + 1 < T_) {
            const long g = gbase + (long)(t+1)*D_;
            rx = values[g]; rm = masks[g]; rd = deltas[g];
        }
        const float invt = minv[t];

        // ---- A1: h *= gamma_h = exp(-relu(d @ W_td_h.T + b_td_h)) ----
        {
            const int b = tid >> 4;
            const int j0 = (tid & 15) * 8;
            float dv[D_];
            #pragma unroll
            for (int k = 0; k < D_; ++k) dv[k] = dsl[b*8+k];
            #pragma unroll
            for (int r = 0; r < 8; ++r) {
                const int j = j0 + r;
                float s = btdh[j];
                #pragma unroll
                for (int k = 0; k < D_; ++k) s = fmaf(dv[k], wtdh[j*D_+k], s);
                h_lds[b*132+j] *= __expf(-fmaxf(s, 0.f));
            }
        }
        __syncthreads();

        // ---- A2: x_h = h @ W_hist.T + b_hist ; gamma_x ; x_c ----
        if (tid < NB*D_) {
            const int b = lb, i = li;
            float s = bhist[i];
            #pragma unroll
            for (int k = 0; k < H_; k += 4) {
                float4 hv = *(const float4*)&h_lds[b*132+k];
                float4 wv = *(const float4*)&whist[i*H_+k];
                s = fmaf(hv.x, wv.x, s); s = fmaf(hv.y, wv.y, s);
                s = fmaf(hv.z, wv.z, s); s = fmaf(hv.w, wv.w, s);
            }
            xh[b*8+i] = s;
            const float mv = msh[b*8+i], xv = xs[b*8+i], dv = dsl[b*8+i];
            xcb[b*8+i] = mv*xv + (1.f-mv)*s;
            gx[b*8+i]  = __expf(-fmaxf(fmaf(dv, tdx[i], btdx[i]), 0.f));
        }
        __syncthreads();

        // ---- A3: z_h, alpha, c_h, c_c, imputation + loss terms ----
        if (tid < NB*D_) {
            const int b = lb, i = li;
            float zh = bfeat[i];
            #pragma unroll
            for (int k = 0; k < D_; ++k) zh = fmaf(wf[i*D_+k], xcb[b*8+k], zh);
            float al = bcomb[i];
            #pragma unroll
            for (int k = 0; k < D_; ++k) al = fmaf(wcomb[i*14+k],   gx[b*8+k], al);
            #pragma unroll
            for (int k = 0; k < D_; ++k) al = fmaf(wcomb[i*14+7+k], msh[b*8+k], al);
            const float xhv = xh[b*8+i];
            const float ch  = al*zh + (1.f-al)*xhv;
            const float mv = msh[b*8+i], xv = xs[b*8+i];
            const float cc = mv*xv + (1.f-mv)*ch;
            out[(size_t)OUT_IMP + (size_t)(b0+b)*TD_ + t*D_ + i] = cc;
            inbuf[b*16+i] = cc;
            lacc = fmaf((fabsf(xv-xhv) + fabsf(xv-zh) + fabsf(xv-ch)) * mv, invt, lacc);
        }
        __syncthreads();

        // ---- B: gates = inputs @ W_ih.T + h @ W_hh.T + (b_ih+b_hh) ----
        float4 a00 = *(const float4*)&biasg[          jj*4];
        float4 a01 = *(const float4*)&biasg[H_     + jj*4];
        float4 a02 = *(const float4*)&biasg[2*H_   + jj*4];
        float4 a03 = *(const float4*)&biasg[3*H_   + jj*4];
        float4 a10 = a00, a11 = a01, a12 = a02, a13 = a03;

        #pragma unroll
        for (int k = 0; k < 14; ++k) {
            const float i0 = inbuf[bA*16+k];
            const float i1 = inbuf[bB*16+k];
            float4 w0 = wih4[k*128 +      jj];
            float4 w1 = wih4[k*128 + 32 + jj];
            float4 w2 = wih4[k*128 + 64 + jj];
            float4 w3 = wih4[k*128 + 96 + jj];
            FMA4(a00,i0,w0); FMA4(a01,i0,w1); FMA4(a02,i0,w2); FMA4(a03,i0,w3);
            FMA4(a10,i1,w0); FMA4(a11,i1,w1); FMA4(a12,i1,w2); FMA4(a13,i1,w3);
        }

        for (int k0 = 0; k0 < H_; k0 += 32) {
            __syncthreads();                       // prior stage reads done
            const float4* src = whhT4 + k0*128;
            #pragma unroll
            for (int r = 0; r < 8; ++r) stage4[tid + NTHR*r] = src[tid + NTHR*r];
            __syncthreads();
            #pragma unroll
            for (int kk4 = 0; kk4 < 8; ++kk4) {
                float4 hv0 = *(const float4*)&h_lds[bA*132 + k0 + kk4*4];
                float4 hv1 = *(const float4*)&h_lds[bB*132 + k0 + kk4*4];
                float h0a[4] = {hv0.x, hv0.y, hv0.z, hv0.w};
                float h1a[4] = {hv1.x, hv1.y, hv1.z, hv1.w};
                #pragma unroll
                for (int u = 0; u < 4; ++u) {
                    const int kk = kk4*4 + u;
                    float4 w0 = stage4[kk*128 +      jj];
                    float4 w1 = stage4[kk*128 + 32 + jj];
                    float4 w2 = stage4[kk*128 + 64 + jj];
                    float4 w3 = stage4[kk*128 + 96 + jj];
                    FMA4(a00,h0a[u],w0); FMA4(a01,h0a[u],w1); FMA4(a02,h0a[u],w2); FMA4(a03,h0a[u],w3);
                    FMA4(a10,h1a[u],w0); FMA4(a11,h1a[u],w1); FMA4(a12,h1a[u],w2); FMA4(a13,h1a[u],w3);
                }
            }
        }
        __syncthreads();   // all h reads done before overwrite

        // ---- LSTM state update (c in registers, h -> LDS) ----
        {
            float4 cn, hn;
            cn.x = sigm(a01.x)*c0.x + sigm(a00.x)*tanh_(a02.x);
            cn.y = sigm(a01.y)*c0.y + sigm(a00.y)*tanh_(a02.y);
            cn.z = sigm(a01.z)*c0.z + sigm(a00.z)*tanh_(a02.z);
            cn.w = sigm(a01.w)*c0.w + sigm(a00.w)*tanh_(a02.w);
            c0 = cn;
            hn.x = sigm(a03.x)*tanh_(cn.x);
            hn.y = sigm(a03.y)*tanh_(cn.y);
            hn.z = sigm(a03.z)*tanh_(cn.z);
            hn.w = sigm(a03.w)*tanh_(cn.w);
            *(float4*)&h_lds[bA*132 + jj*4] = hn;

            cn.x = sigm(a11.x)*c1.x + sigm(a10.x)*tanh_(a12.x);
            cn.y = sigm(a11.y)*c1.y + sigm(a10.y)*tanh_(a12.y);
            cn.z = sigm(a11.z)*c1.z + sigm(a10.z)*tanh_(a12.z);
            cn.w = sigm(a11.w)*c1.w + sigm(a10.w)*tanh_(a12.w);
            c1 = cn;
            hn.x = sigm(a13.x)*tanh_(cn.x);
            hn.y = sigm(a13.y)*tanh_(cn.y);
            hn.z = sigm(a13.z)*tanh_(cn.z);
            hn.w = sigm(a13.w)*tanh_(cn.w);
            *(float4*)&h_lds[bB*132 + jj*4] = hn;
        }
    }
    __syncthreads();

    // ---- x_loss partial reduction ----
    for (int off = 32; off > 0; off >>= 1) lacc += __shfl_down(lacc, off, 64);
    if ((tid & 63) == 0) red[tid >> 6] = lacc;
    __syncthreads();
    if (tid == 0) {
        float s = 0.f;
        #pragma unroll
        for (int w = 0; w < 8; ++w) s += red[w];
        atomicAdd(&ws[WS_ACC], s);
    }
    // ---- final h -> workspace ----
    for (int i = tid; i < NB*H_; i += NTHR)
        ws[WS_HFIN + (size_t)b0*H_ + i] = h_lds[(i >> 7)*132 + (i & 127)];
}

// ================= classification head =================
__global__ __launch_bounds__(128) void rits_head(
    const float* __restrict__ probs, const float* __restrict__ ancillary, const int* __restrict__ labels,
    const float* __restrict__ W_anc, const float* __restrict__ b_anc,
    const float* __restrict__ b_cat,
    const float* __restrict__ W_out, const float* __restrict__ b_out,
    float* __restrict__ ws, float* __restrict__ out)
{
    __shared__ float hb[MB*H_];
    __shared__ float ancl[MB*52];
    __shared__ float hc[MB*H_];
    __shared__ float lg[MB*32];
    __shared__ float smx[MB], sinv[MB], ysum[MB];
    __shared__ float sq[MB*32];
    const int tid = threadIdx.x;
    const int bb0 = blockIdx.x * MB;

    for (int i = tid; i < MB*H_; i += 128) hb[i] = ws[WS_HFIN + (size_t)bb0*H_ + i];
    for (int i = tid; i < MB*E_; i += 128) {
        int b = i / E_, e = i - b*E_;
        float s = b_anc[e];
        #pragma unroll
        for (int a = 0; a < A_; ++a) s = fmaf(ancillary[(bb0+b)*A_ + a], W_anc[e*A_ + a], s);
        ancl[b*52+e] = fmaxf(s, 0.f);
    }
    __syncthreads();
    {   // h_cat = relu(concat(h, anc) @ W_cat.T + b_cat)
        const int j = tid;
        float s[MB];
        #pragma unroll
        for (int b = 0; b < MB; ++b) s[b] = b_cat[j];
        const float* wc = ws + WS_WCATT;
        for (int k = 0; k < H_; ++k) {
            float w = wc[k*H_ + j];
            #pragma unroll
            for (int b = 0; b < MB; ++b) s[b] = fmaf(hb[b*H_+k], w, s[b]);
        }
        for (int k = 0; k < E_; ++k) {
            float w = wc[(H_+k)*H_ + j];
            #pragma unroll
            for (int b = 0; b < MB; ++b) s[b] = fmaf(ancl[b*52+k], w, s[b]);
        }
        #pragma unroll
        for (int b = 0; b < MB; ++b) hc[b*H_+j] = fmaxf(s[b], 0.f);
    }
    __syncthreads();
    for (int i = tid; i < MB*O_; i += 128) {
        int b = i / O_, o = i - b*O_;
        float s = b_out[o];
        for (int k = 0; k < H_; ++k) s = fmaf(hc[b*H_+k], W_out[o*H_+k], s);
        lg[b*32+o] = s;
    }
    __syncthreads();
    if (tid < MB) {
        float mx = -1e30f;
        for (int o = 0; o < O_; ++o) mx = fmaxf(mx, lg[tid*32+o]);
        float se = 0.f;
        for (int o = 0; o < O_; ++o) se += __expf(lg[tid*32+o] - mx);
        smx[tid] = mx; sinv[tid] = 1.f / se;
    }
    __syncthreads();
    for (int i = tid; i < MB*O_; i += 128) {
        int b = i / O_, o = i - b*O_;
        float y = __expf(lg[b*32+o] - smx[b]) * sinv[b];
        out[OUT_YH + (size_t)(bb0+b)*O_ + o] = y;
        float d = y - probs[(size_t)(bb0+b)*O_ + o];
        sq[b*32+o] = d*d;
    }
    __syncthreads();
    if (tid < MB) {
        float s = 0.f;
        for (int o = 0; o < O_; ++o) s += sq[tid*32+o];
        ysum[tid] = s;
        out[OUT_LAB + bb0 + tid] = (float)labels[bb0 + tid];
    }
    __syncthreads();
    if (tid == 0) {
        float s = 0.f;
        #pragma unroll
        for (int b = 0; b < MB; ++b) s += ysum[b];
        atomicAdd(&ws[WS_ACC+1], s);
    }
}

// ================= finalize scalars =================
__global__ void rits_fin(const float* __restrict__ ws, float* __restrict__ out)
{
    if (blockIdx.x == 0 && threadIdx.x == 0) {
        float xl = ws[WS_ACC] * 0.3f;                       // IMPUTE_W
        float yl = ws[WS_ACC+1] * (1.0f / (8192.0f + 1e-5f)); // LABEL_W=1
        out[0] = xl; out[1] = yl; out[2] = xl + yl;
    }
}

extern "C" void kernel_launch(void* const* d_in, const int* in_sizes, int n_in,
                              void* d_out, int out_size, void* d_ws, size_t ws_size,
                              hipStream_t stream)
{
    const float* values = (const float*)d_in[0];
    const float* masks  = (const float*)d_in[1];
    const float* deltas = (const float*)d_in[2];
    const float* probs  = (const float*)d_in[3];
    const float* ancil  = (const float*)d_in[4];
    const int*   labels = (const int*)  d_in[5];
    const float* W_td_h = (const float*)d_in[6];
    const float* b_td_h = (const float*)d_in[7];
    const float* W_td_x = (const float*)d_in[8];
    const float* b_td_x = (const float*)d_in[9];
    const float* W_hist = (const float*)d_in[10];
    const float* b_hist = (const float*)d_in[11];
    const float* W_feat = (const float*)d_in[12];
    const float* b_feat = (const float*)d_in[13];
    const float* W_comb = (const float*)d_in[14];
    const float* b_comb = (const float*)d_in[15];
    const float* W_ih   = (const float*)d_in[16];
    const float* W_hh   = (const float*)d_in[17];
    const float* b_ih   = (const float*)d_in[18];
    const float* b_hh   = (const float*)d_in[19];
    const float* W_anc  = (const float*)d_in[20];
    const float* b_anc  = (const float*)d_in[21];
    const float* W_cat  = (const float*)d_in[22];
    const float* b_cat  = (const float*)d_in[23];
    const float* W_out  = (const float*)d_in[24];
    const float* b_out  = (const float*)d_in[25];
    float* ws  = (float*)d_ws;
    float* out = (float*)d_out;

    hipLaunchKernelGGL(rits_prep, dim3((G_*H_ + 14*G_ + H_*178 + 255)/256), dim3(256), 0, stream,
                       W_hh, W_ih, W_cat, ws);
    hipLaunchKernelGGL(rits_msum, dim3(T_), dim3(256), 0, stream, masks, ws);
    hipLaunchKernelGGL(rits_main, dim3(B_/NB), dim3(NTHR), 0, stream,
                       values, masks, deltas, W_td_h, b_td_h, W_td_x, b_td_x,
                       W_hist, b_hist, W_feat, b_feat, W_comb, b_comb,
                       b_ih, b_hh, ws, out);
    hipLaunchKernelGGL(rits_head, dim3(B_/MB), dim3(128), 0, stream,
                       probs, ancil, labels, W_anc, b_anc, b_cat, W_out, b_out, ws, out);
    hipLaunchKernelGGL(rits_fin, dim3(1), dim3(1), 0, stream, ws, out);
}

// Round 3
// 1040.765 us; speedup vs baseline: 6.4889x; 6.4889x over previous
//
#include <hip/hip_runtime.h>
#include <math.h>

// ---------------- problem constants ----------------
#define B_ 8192
#define T_ 223
#define D_ 7
#define H_ 128
#define G_ 512      // 4*H
#define E_ 50
#define O_ 29
#define A_ 9
#define TD_ (T_*D_)     // 1561
#define NB 32           // batch rows per block (main kernel)
#define NTHR 512
#define MB 8            // batch rows per block (head kernel)

// ---------------- workspace layout (float offsets) ----------------
#define WS_MINV  0                            // 1/(msum_t+1e-5), T floats
#define WS_ACC   (WS_MINV + T_)               // [0]=x_loss raw sum, [1]=y_loss raw sum
#define WS_WCATT (WS_ACC + 2)                 // [178][128] transposed W_cat
#define WS_HFIN  (WS_WCATT + 178*H_)          // final h, [B][128] fp32

// ---------------- output layout (floats) ----------------
#define OUT_YH  3
#define OUT_IMP (OUT_YH + B_*O_)              // 237571
#define OUT_LAB (OUT_IMP + B_*T_*D_)          // 13025283

typedef __attribute__((ext_vector_type(8))) short short8;   // 8 bf16 = 4 VGPRs
typedef __attribute__((ext_vector_type(4))) float floatx4;
#define MFMA16(Av,Bv,Cv) __builtin_amdgcn_mfma_f32_16x16x32_bf16((Av),(Bv),(Cv),0,0,0)

__device__ __forceinline__ unsigned short f2bf(float f) {   // RNE fp32->bf16
    unsigned int u = __builtin_bit_cast(unsigned int, f);
    return (unsigned short)((u + 0x7FFFu + ((u >> 16) & 1u)) >> 16);
}
__device__ __forceinline__ float bf2f(unsigned short s) {
    unsigned int u = ((unsigned int)s) << 16;
    return __builtin_bit_cast(float, u);
}
__device__ __forceinline__ float rcp_(float x)  { return __builtin_amdgcn_rcpf(x); }
__device__ __forceinline__ float sigm(float x)  { return rcp_(1.f + __expf(-x)); }
__device__ __forceinline__ float tanh_(float x) { return 1.f - 2.f*rcp_(1.f + __expf(2.f*x)); }

// ================= prep: W_cat transpose + zero accumulators =================
__global__ void rits_prep(const float* __restrict__ W_cat, float* __restrict__ ws)
{
    int idx = blockIdx.x * 256 + threadIdx.x;
    if (idx < H_*178) {                      // W_cat [128][178] -> [178][128]
        int j = idx / 178, k = idx - j*178;
        ws[WS_WCATT + k*H_ + j] = W_cat[idx];
    }
    if (idx < 2) ws[WS_ACC + idx] = 0.f;
}

// ================= per-step mask sums =================
__global__ void rits_msum(const float* __restrict__ masks, float* __restrict__ ws)
{
    const int t = blockIdx.x, tid = threadIdx.x;
    float s = 0.f;
    for (int i = tid; i < B_*D_; i += 256) {
        int b = i / D_, q = i - b*D_;
        s += masks[b*TD_ + t*D_ + q];
    }
    for (int off = 32; off > 0; off >>= 1) s += __shfl_down(s, off, 64);
    __shared__ float r[4];
    if ((tid & 63) == 0) r[tid >> 6] = s;
    __syncthreads();
    if (tid == 0) ws[WS_MINV + t] = 1.f / (r[0]+r[1]+r[2]+r[3] + 1e-5f);
}

// ================= main scan kernel (MFMA) =================
// Formulation: D[gate j][batch b] = sum_k W_ext[j][k] * hext[b][k]
//   A-frags (W) persistent in VGPRs; B-frags (h / c_c,m ext) from LDS hbuf.
// Wave w owns gate M-tiles {w, 8+w, 16+w, 24+w} (one per i/f/g/o quadrant) so
// each lane's C rows give i,f,g,o for the SAME hidden j = w*16+quad*4+r.
__global__ __launch_bounds__(NTHR, 2) void rits_main(
    const float* __restrict__ values, const float* __restrict__ masks, const float* __restrict__ deltas,
    const float* __restrict__ W_td_h, const float* __restrict__ b_td_h,
    const float* __restrict__ W_td_x, const float* __restrict__ b_td_x,
    const float* __restrict__ W_hist, const float* __restrict__ b_hist,
    const float* __restrict__ W_feat, const float* __restrict__ b_feat,
    const float* __restrict__ W_comb, const float* __restrict__ b_comb,
    const float* __restrict__ W_ih, const float* __restrict__ W_hh,
    const float* __restrict__ b_ih, const float* __restrict__ b_hh,
    float* __restrict__ ws, float* __restrict__ out)
{
    // B-operand buffer: rows=batch(32), cols bf16: 0..127=h, 128..134=c_c,
    // 135..141=m, 142..159=0. Row stride 168 bf16 = 336B (16B-aligned, 2-way banks)
    __shared__ __attribute__((aligned(16))) unsigned short hbuf[NB*168];
    __shared__ __attribute__((aligned(16))) unsigned short dbuf[NB*72];   // d(t+1) bf16, cols 7..31 = 0
    __shared__ __attribute__((aligned(16))) unsigned short whis_lds[16*136]; // W_hist bf16, rows 7..15 = 0
    __shared__ float xs[NB*8], msh[NB*8], dsl[NB*8];
    __shared__ float xh_l[NB*8], xc_l[NB*8], gx_l[NB*8];
    __shared__ float bhist_l[8], tdx_l[8], btdx_l[8];
    __shared__ float impbuf[NB*16*7];       // 16-step imputation buffer (fp32)
    __shared__ float red[8];

    const int tid  = threadIdx.x;
    const int b0   = blockIdx.x * NB;
    const int lane = tid & 63;
    const int w    = tid >> 6;      // wave 0..7
    const int quad = lane >> 4;
    const int l15  = lane & 15;

    // ---- one-time LDS init ----
    for (int i = tid; i < NB*168; i += NTHR) hbuf[i] = 0;
    for (int i = tid; i < NB*72;  i += NTHR) dbuf[i] = 0;
    for (int i = tid; i < 16*136; i += NTHR) {
        int r = i / 136, c = i - r*136;
        whis_lds[i] = (r < 7 && c < 128) ? f2bf(W_hist[r*H_ + c]) : 0;
    }
    if (tid < 8) {
        bhist_l[tid] = (tid < 7) ? b_hist[tid] : 0.f;
        tdx_l[tid]   = (tid < 7) ? W_td_x[tid*D_ + tid] : 0.f;
        btdx_l[tid]  = (tid < 7) ? b_td_x[tid] : 0.f;
    }

    // ---- persistent weight fragments (per lane) ----
    short8 whhf[4][4];   // [gate c][kstep]  A[j=l15 of tile][k=quad*8+e]
    short8 winf[4];      // input kstep (k_ext 0..13 = W_ih, rest 0)
    short8 wtdf;         // W_td_h frag for gamma_h MFMA (j = w*16+l15, k<7)
    float  biasg_r[4][4];
    float  btdh_r[4];
    {
        union UU { short8 v; unsigned short u[8]; } fr;
        #pragma unroll
        for (int c = 0; c < 4; ++c) {
            const int j = (c*8 + w)*16 + l15;
            #pragma unroll
            for (int s = 0; s < 4; ++s) {
                const float* p = W_hh + j*H_ + s*32 + quad*8;
                #pragma unroll
                for (int e = 0; e < 8; ++e) fr.u[e] = f2bf(p[e]);
                whhf[c][s] = fr.v;
            }
            #pragma unroll
            for (int e = 0; e < 8; ++e) {
                int k = quad*8 + e;
                fr.u[e] = (k < 14) ? f2bf(W_ih[j*14 + k]) : (unsigned short)0;
            }
            winf[c] = fr.v;
            #pragma unroll
            for (int r = 0; r < 4; ++r) {
                int jj = (c*8 + w)*16 + quad*4 + r;
                biasg_r[c][r] = b_ih[jj] + b_hh[jj];
            }
        }
        #pragma unroll
        for (int e = 0; e < 8; ++e) {
            int k = quad*8 + e;
            fr.u[e] = (k < 7) ? f2bf(W_td_h[(w*16 + l15)*D_ + k]) : (unsigned short)0;
        }
        wtdf = fr.v;
        #pragma unroll
        for (int r = 0; r < 4; ++r) btdh_r[r] = b_td_h[w*16 + quad*4 + r];
    }

    // ---- A3 per-thread state ----
    const bool ldr = (tid < NB*D_);
    const int  lb  = tid / D_, li = tid - (tid/D_)*D_;
    float wfr[7], wcr[14], bfr = 0.f, bcr = 0.f;
    if (ldr) {
        #pragma unroll
        for (int k = 0; k < 7; ++k)  wfr[k] = (k == li) ? 0.f : W_feat[li*D_ + k];
        #pragma unroll
        for (int k = 0; k < 14; ++k) wcr[k] = W_comb[li*14 + k];
        bfr = b_feat[li];  bcr = b_comb[li];
    }

    float c_st[2][4] = {{0,0,0,0},{0,0,0,0}};
    float lacc = 0.f;

    // input prefetch (regs hold step-t data at loop top)
    const long gbase = (long)(b0 + lb)*TD_ + li;
    float rx = 0.f, rm = 0.f, rd = 0.f;
    if (ldr) { rx = values[gbase]; rm = masks[gbase]; rd = deltas[gbase]; }

    const float* minv = ws + WS_MINV;

    for (int t = 0; t < T_; ++t) {
        if (ldr) { xs[lb*8+li] = rx; msh[lb*8+li] = rm; dsl[lb*8+li] = rd; }
        __syncthreads();                       // [S] stage + prev h-writes visible
        if (ldr && t + 1 < T_) {
            const long g = gbase + (long)(t+1)*D_;
            rx = values[g]; rm = masks[g]; rd = deltas[g];
        }

        // ---- B1: gate h-part (+ x_h on wave 7). h in hbuf is ALREADY decayed ----
        floatx4 acc[4][2];
        #pragma unroll
        for (int c = 0; c < 4; ++c)
            #pragma unroll
            for (int nt = 0; nt < 2; ++nt) {
                floatx4 a = { biasg_r[c][0], biasg_r[c][1], biasg_r[c][2], biasg_r[c][3] };
                acc[c][nt] = a;
            }
        floatx4 xh0 = {0,0,0,0}, xh1 = {0,0,0,0};
        #pragma unroll
        for (int s = 0; s < 4; ++s) {
            short8 hb0 = *(const short8*)&hbuf[l15*168       + s*32 + quad*8];
            short8 hb1 = *(const short8*)&hbuf[(16+l15)*168  + s*32 + quad*8];
            #pragma unroll
            for (int c = 0; c < 4; ++c) {
                acc[c][0] = MFMA16(whhf[c][s], hb0, acc[c][0]);
                acc[c][1] = MFMA16(whhf[c][s], hb1, acc[c][1]);
            }
            if (w == 7) {
                short8 wh = *(const short8*)&whis_lds[l15*136 + s*32 + quad*8];
                xh0 = MFMA16(wh, hb0, xh0);
                xh1 = MFMA16(wh, hb1, xh1);
            }
        }
        // wave 7: finish x_h, compute x_c / gamma_x, publish to LDS
        if (w == 7 && quad < 2) {
            #pragma unroll
            for (int nt = 0; nt < 2; ++nt) {
                const int b = nt*16 + l15;
                floatx4 xv = nt ? xh1 : xh0;
                #pragma unroll
                for (int r = 0; r < 4; ++r) {
                    const int i = quad*4 + r;
                    if (i < 7) {
                        float xhv = xv[r] + bhist_l[i];
                        float x = xs[b*8+i], m = msh[b*8+i], d = dsl[b*8+i];
                        xh_l[b*8+i] = xhv;
                        xc_l[b*8+i] = m*x + (1.f-m)*xhv;
                        gx_l[b*8+i] = __expf(-fmaxf(fmaf(d, tdx_l[i], btdx_l[i]), 0.f));
                    }
                }
            }
        }
        __syncthreads();                       // [B] x_h / x_c / gamma_x ready

        // ---- A3: z_h, alpha, c_h, c_c, imputation, loss; write ext cols + dbuf ----
        if (ldr) {
            const int b = lb, i = li;
            const float invt = minv[t];
            const float x = xs[b*8+i], m = msh[b*8+i];
            float zh = bfr;
            #pragma unroll
            for (int k = 0; k < 7; ++k) zh = fmaf(wfr[k], xc_l[b*8+k], zh);
            float al = bcr;
            #pragma unroll
            for (int k = 0; k < 7; ++k) al = fmaf(wcr[k],   gx_l[b*8+k], al);
            #pragma unroll
            for (int k = 0; k < 7; ++k) al = fmaf(wcr[7+k], msh[b*8+k], al);
            const float xhv = xh_l[b*8+i];
            const float ch  = al*zh + (1.f-al)*xhv;
            const float cc  = m*x + (1.f-m)*ch;
            impbuf[(b*16 + (t & 15))*7 + i] = cc;
            hbuf[b*168 + 128 + i] = f2bf(cc);
            hbuf[b*168 + 135 + i] = f2bf(m);
            dbuf[b*72 + i] = f2bf(rd);         // d(t+1) for fused decay
            lacc = fmaf((fabsf(x-xhv) + fabsf(x-zh) + fabsf(x-ch)) * m, invt, lacc);
        }
        __syncthreads();                       // [C] c_c/m ext + dbuf ready

        // ---- B2: input part ----
        {
            short8 ib0 = *(const short8*)&hbuf[l15*168      + 128 + quad*8];
            short8 ib1 = *(const short8*)&hbuf[(16+l15)*168 + 128 + quad*8];
            #pragma unroll
            for (int c = 0; c < 4; ++c) {
                acc[c][0] = MFMA16(winf[c], ib0, acc[c][0]);
                acc[c][1] = MFMA16(winf[c], ib1, acc[c][1]);
            }
        }
        // ---- fused gamma_h(t+1) via MFMA on d(t+1) ----
        floatx4 g0 = {0,0,0,0}, g1 = {0,0,0,0};
        const bool dec = (t + 1 < T_);
        if (dec) {
            short8 df0 = *(const short8*)&dbuf[l15*72      + quad*8];
            short8 df1 = *(const short8*)&dbuf[(16+l15)*72 + quad*8];
            floatx4 z = {0,0,0,0};
            g0 = MFMA16(wtdf, df0, z);
            g1 = MFMA16(wtdf, df1, z);
        }
        // ---- LSTM update; write h (pre-decayed for next step) ----
        #pragma unroll
        for (int nt = 0; nt < 2; ++nt) {
            const int b = nt*16 + l15;
            floatx4 gg = nt ? g1 : g0;
            #pragma unroll
            for (int r = 0; r < 4; ++r) {
                float ig = acc[0][nt][r], fg = acc[1][nt][r];
                float gv = acc[2][nt][r], og = acc[3][nt][r];
                float cn = sigm(fg)*c_st[nt][r] + sigm(ig)*tanh_(gv);
                c_st[nt][r] = cn;
                float hn = sigm(og)*tanh_(cn);
                if (dec) hn *= __expf(-fmaxf(gg[r] + btdh_r[r], 0.f));
                hbuf[b*168 + w*16 + quad*4 + r] = f2bf(hn);
            }
        }

        // ---- imputation flush (contiguous 28B runs, 16 steps at a time) ----
        if ((t & 15) == 15 || t == T_ - 1) {
            const int t0 = t & ~15;
            const int b  = tid >> 4, c16 = tid & 15;
            if (t0 + c16 <= t) {
                float* gp = out + (size_t)OUT_IMP + (size_t)(b0+b)*TD_ + (size_t)(t0+c16)*D_;
                const float* lp = &impbuf[(b*16 + c16)*7];
                #pragma unroll
                for (int e = 0; e < 7; ++e) gp[e] = lp[e];
            }
        }
    }
    __syncthreads();

    // ---- x_loss partial reduction ----
    for (int off = 32; off > 0; off >>= 1) lacc += __shfl_down(lacc, off, 64);
    if ((tid & 63) == 0) red[tid >> 6] = lacc;
    __syncthreads();
    if (tid == 0) {
        float s = 0.f;
        #pragma unroll
        for (int q = 0; q < 8; ++q) s += red[q];
        atomicAdd(&ws[WS_ACC], s);
    }
    // ---- final h -> workspace (fp32) ----
    for (int i = tid; i < NB*H_; i += NTHR) {
        int b = i >> 7, j = i & 127;
        ws[WS_HFIN + (size_t)(b0+b)*H_ + j] = bf2f(hbuf[b*168 + j]);
    }
}

// ================= classification head =================
__global__ __launch_bounds__(128) void rits_head(
    const float* __restrict__ probs, const float* __restrict__ ancillary, const int* __restrict__ labels,
    const float* __restrict__ W_anc, const float* __restrict__ b_anc,
    const float* __restrict__ b_cat,
    const float* __restrict__ W_out, const float* __restrict__ b_out,
    float* __restrict__ ws, float* __restrict__ out)
{
    __shared__ float hb[MB*H_];
    __shared__ float ancl[MB*52];
    __shared__ float hc[MB*H_];
    __shared__ float lg[MB*32];
    __shared__ float smx[MB], sinv[MB], ysum[MB];
    __shared__ float sq[MB*32];
    const int tid = threadIdx.x;
    const int bb0 = blockIdx.x * MB;

    for (int i = tid; i < MB*H_; i += 128) hb[i] = ws[WS_HFIN + (size_t)bb0*H_ + i];
    for (int i = tid; i < MB*E_; i += 128) {
        int b = i / E_, e = i - b*E_;
        float s = b_anc[e];
        #pragma unroll
        for (int a = 0; a < A_; ++a) s = fmaf(ancillary[(bb0+b)*A_ + a], W_anc[e*A_ + a], s);
        ancl[b*52+e] = fmaxf(s, 0.f);
    }
    __syncthreads();
    {
        const int j = tid;
        float s[MB];
        #pragma unroll
        for (int b = 0; b < MB; ++b) s[b] = b_cat[j];
        const float* wc = ws + WS_WCATT;
        for (int k = 0; k < H_; ++k) {
            float wv = wc[k*H_ + j];
            #pragma unroll
            for (int b = 0; b < MB; ++b) s[b] = fmaf(hb[b*H_+k], wv, s[b]);
        }
        for (int k = 0; k < E_; ++k) {
            float wv = wc[(H_+k)*H_ + j];
            #pragma unroll
            for (int b = 0; b < MB; ++b) s[b] = fmaf(ancl[b*52+k], wv, s[b]);
        }
        #pragma unroll
        for (int b = 0; b < MB; ++b) hc[b*H_+j] = fmaxf(s[b], 0.f);
    }
    __syncthreads();
    for (int i = tid; i < MB*O_; i += 128) {
        int b = i / O_, o = i - b*O_;
        float s = b_out[o];
        for (int k = 0; k < H_; ++k) s = fmaf(hc[b*H_+k], W_out[o*H_+k], s);
        lg[b*32+o] = s;
    }
    __syncthreads();
    if (tid < MB) {
        float mx = -1e30f;
        for (int o = 0; o < O_; ++o) mx = fmaxf(mx, lg[tid*32+o]);
        float se = 0.f;
        for (int o = 0; o < O_; ++o) se += __expf(lg[tid*32+o] - mx);
        smx[tid] = mx; sinv[tid] = 1.f / se;
    }
    __syncthreads();
    for (int i = tid; i < MB*O_; i += 128) {
        int b = i / O_, o = i - b*O_;
        float y = __expf(lg[b*32+o] - smx[b]) * sinv[b];
        out[OUT_YH + (size_t)(bb0+b)*O_ + o] = y;
        float d = y - probs[(size_t)(bb0+b)*O_ + o];
        sq[b*32+o] = d*d;
    }
    __syncthreads();
    if (tid < MB) {
        float s = 0.f;
        for (int o = 0; o < O_; ++o) s += sq[tid*32+o];
        ysum[tid] = s;
        out[OUT_LAB + bb0 + tid] = (float)labels[bb0 + tid];
    }
    __syncthreads();
    if (tid == 0) {
        float s = 0.f;
        #pragma unroll
        for (int b = 0; b < MB; ++b) s += ysum[b];
        atomicAdd(&ws[WS_ACC+1], s);
    }
}

// ================= finalize scalars =================
__global__ void rits_fin(const float* __restrict__ ws, float* __restrict__ out)
{
    if (blockIdx.x == 0 && threadIdx.x == 0) {
        float xl = ws[WS_ACC] * 0.3f;
        float yl = ws[WS_ACC+1] * (1.0f / (8192.0f + 1e-5f));
        out[0] = xl; out[1] = yl; out[2] = xl + yl;
    }
}

extern "C" void kernel_launch(void* const* d_in, const int* in_sizes, int n_in,
                              void* d_out, int out_size, void* d_ws, size_t ws_size,
                              hipStream_t stream)
{
    const float* values = (const float*)d_in[0];
    const float* masks  = (const float*)d_in[1];
    const float* deltas = (const float*)d_in[2];
    const float* probs  = (const float*)d_in[3];
    const float* ancil  = (const float*)d_in[4];
    const int*   labels = (const int*)  d_in[5];
    const float* W_td_h = (const float*)d_in[6];
    const float* b_td_h = (const float*)d_in[7];
    const float* W_td_x = (const float*)d_in[8];
    const float* b_td_x = (const float*)d_in[9];
    const float* W_hist = (const float*)d_in[10];
    const float* b_hist = (const float*)d_in[11];
    const float* W_feat = (const float*)d_in[12];
    const float* b_feat = (const float*)d_in[13];
    const float* W_comb = (const float*)d_in[14];
    const float* b_comb = (const float*)d_in[15];
    const float* W_ih   = (const float*)d_in[16];
    const float* W_hh   = (const float*)d_in[17];
    const float* b_ih   = (const float*)d_in[18];
    const float* b_hh   = (const float*)d_in[19];
    const float* W_anc  = (const float*)d_in[20];
    const float* b_anc  = (const float*)d_in[21];
    const float* W_cat  = (const float*)d_in[22];
    const float* b_cat  = (const float*)d_in[23];
    const float* W_out  = (const float*)d_in[24];
    const float* b_out  = (const float*)d_in[25];
    float* ws  = (float*)d_ws;
    float* out = (float*)d_out;

    hipLaunchKernelGGL(rits_prep, dim3((H_*178 + 255)/256), dim3(256), 0, stream, W_cat, ws);
    hipLaunchKernelGGL(rits_msum, dim3(T_), dim3(256), 0, stream, masks, ws);
    hipLaunchKernelGGL(rits_main, dim3(B_/NB), dim3(NTHR), 0, stream,
                       values, masks, deltas, W_td_h, b_td_h, W_td_x, b_td_x,
                       W_hist, b_hist, W_feat, b_feat, W_comb, b_comb,
                       W_ih, W_hh, b_ih, b_hh, ws, out);
    hipLaunchKernelGGL(rits_head, dim3(B_/MB), dim3(128), 0, stream,
                       probs, ancil, labels, W_anc, b_anc, b_cat, W_out, b_out, ws, out);
    hipLaunchKernelGGL(rits_fin, dim3(1), dim3(1), 0, stream, ws, out);
}